// Round 1
// baseline (3155.680 us; speedup 1.0000x reference)
//
#include <hip/hip_runtime.h>

// ConvLSTM1D: B=8, T=128, CIN=64, COUT=64, H=256
// Reference: per step t
//   cat = concat([x_t, h], ch)                       (B, 128, H)
//   conv = conv1d(cat, w[256,128,3], SAME) + bias    (B, 256, H)
//   i,f,g,o = split(conv, 4, ch)
//   i = sigmoid(i + wci*c); f = sigmoid(f + wcf*c)
//   c_new = f*c + i*tanh(g)
//   o = sigmoid(o + wco*c_new); h_new = o*tanh(c_new)
// Outputs: hs [B,T,COUT,H], cs [B,T,COUT,H] concatenated flat in d_out.
//
// Baseline strategy (round 0): 128 sequential launches; d_out doubles as the
// recurrent state storage (step t reads t-1's slices). Lanes span H so data
// loads are coalesced and weight addresses are wave-uniform (scalarizable).

constexpr int Bn    = 8;
constexpr int Tn    = 128;
constexpr int CINn  = 64;
constexpr int COUTn = 64;
constexpr int Hn    = 256;
constexpr int ICAT  = CINn + COUTn;  // 128

constexpr int PT    = 64;            // p positions per block (one per lane)
constexpr int WAVES = 4;             // waves per block (256 threads)
constexpr int COJ   = 2;             // output channels per wave
constexpr int CO_PER_BLOCK = WAVES * COJ;  // 8

__device__ __forceinline__ float sigmoidf_(float v) {
    return 1.0f / (1.0f + __expf(-v));
}

__global__ __launch_bounds__(256) void convlstm_step(
    const float* __restrict__ x,     // [B][T][CIN][H]
    const float* __restrict__ h0,    // [B][COUT][H]
    const float* __restrict__ c0,    // [B][COUT][H]
    const float* __restrict__ w,     // [4*COUT][ICAT][3]
    const float* __restrict__ bias,  // [4*COUT]
    const float* __restrict__ wci,   // [COUT][H]
    const float* __restrict__ wcf,   // [COUT][H]
    const float* __restrict__ wco,   // [COUT][H]
    float* __restrict__ hs,          // [B][T][COUT][H]
    float* __restrict__ cs,          // [B][T][COUT][H]
    int t)
{
    const int lane = threadIdx.x & 63;
    const int wv   = __builtin_amdgcn_readfirstlane((int)(threadIdx.x >> 6));
    const int p    = blockIdx.x * PT + lane;
    const int b    = blockIdx.y;
    const int co0  = blockIdx.z * CO_PER_BLOCK + wv * COJ;  // wave-uniform

    const float* xt = x + (size_t)(b * Tn + t) * CINn * Hn;
    const float* hp = (t == 0) ? (h0 + (size_t)b * COUTn * Hn)
                               : (hs + (size_t)(b * Tn + (t - 1)) * COUTn * Hn);
    const float* cp = (t == 0) ? (c0 + (size_t)b * COUTn * Hn)
                               : (cs + (size_t)(b * Tn + (t - 1)) * COUTn * Hn);

    float acc[COJ][4];
#pragma unroll
    for (int j = 0; j < COJ; ++j)
#pragma unroll
        for (int g = 0; g < 4; ++g)
            acc[j][g] = bias[g * COUTn + co0 + j];  // wave-uniform -> s_load

    // ---- x half of cat (ic = 0..63) ----
#pragma unroll 4
    for (int ic = 0; ic < CINn; ++ic) {
        const float* src = xt + (size_t)ic * Hn;
        const float v1 = src[p];
        const float v0 = (p > 0)      ? src[p - 1] : 0.0f;
        const float v2 = (p < Hn - 1) ? src[p + 1] : 0.0f;
        const float* wic = w + (size_t)ic * 3;
#pragma unroll
        for (int j = 0; j < COJ; ++j) {
#pragma unroll
            for (int g = 0; g < 4; ++g) {
                const float* wr =
                    wic + (size_t)(g * COUTn + co0 + j) * (ICAT * 3);
                acc[j][g] = fmaf(wr[0], v0,
                            fmaf(wr[1], v1,
                            fmaf(wr[2], v2, acc[j][g])));
            }
        }
    }

    // ---- h half of cat (ic = 64..127) ----
#pragma unroll 4
    for (int hc = 0; hc < COUTn; ++hc) {
        const float* src = hp + (size_t)hc * Hn;
        const float v1 = src[p];
        const float v0 = (p > 0)      ? src[p - 1] : 0.0f;
        const float v2 = (p < Hn - 1) ? src[p + 1] : 0.0f;
        const float* wic = w + (size_t)(CINn + hc) * 3;
#pragma unroll
        for (int j = 0; j < COJ; ++j) {
#pragma unroll
            for (int g = 0; g < 4; ++g) {
                const float* wr =
                    wic + (size_t)(g * COUTn + co0 + j) * (ICAT * 3);
                acc[j][g] = fmaf(wr[0], v0,
                            fmaf(wr[1], v1,
                            fmaf(wr[2], v2, acc[j][g])));
            }
        }
    }

    // ---- gates ----
#pragma unroll
    for (int j = 0; j < COJ; ++j) {
        const int co = co0 + j;
        const size_t cidx = (size_t)co * Hn + p;
        const float cprev = cp[cidx];
        const float iv = sigmoidf_(acc[j][0] + wci[cidx] * cprev);
        const float fv = sigmoidf_(acc[j][1] + wcf[cidx] * cprev);
        const float gv = tanhf(acc[j][2]);
        const float cn = fv * cprev + iv * gv;
        const float ov = sigmoidf_(acc[j][3] + wco[cidx] * cn);
        const float hn = ov * tanhf(cn);
        const size_t oidx = ((size_t)(b * Tn + t) * COUTn + co) * Hn + p;
        hs[oidx] = hn;
        cs[oidx] = cn;
    }
}

extern "C" void kernel_launch(void* const* d_in, const int* in_sizes, int n_in,
                              void* d_out, int out_size, void* d_ws, size_t ws_size,
                              hipStream_t stream) {
    (void)in_sizes; (void)n_in; (void)out_size; (void)d_ws; (void)ws_size;

    const float* x    = (const float*)d_in[0];
    const float* h0   = (const float*)d_in[1];
    const float* c0   = (const float*)d_in[2];
    const float* w    = (const float*)d_in[3];
    const float* bias = (const float*)d_in[4];
    const float* wci  = (const float*)d_in[5];
    const float* wcf  = (const float*)d_in[6];
    const float* wco  = (const float*)d_in[7];

    float* hs = (float*)d_out;
    float* cs = hs + (size_t)Bn * Tn * COUTn * Hn;

    dim3 grid(Hn / PT, Bn, COUTn / CO_PER_BLOCK);  // (4, 8, 8) = 256 blocks
    for (int t = 0; t < Tn; ++t) {
        convlstm_step<<<grid, 256, 0, stream>>>(
            x, h0, c0, w, bias, wci, wcf, wco, hs, cs, t);
    }
}

// Round 2
// 2852.563 us; speedup vs baseline: 1.1063x; 1.1063x over previous
//
#include <hip/hip_runtime.h>

// ConvLSTM1D: B=8, T=128, CIN=64, COUT=64, H=256
// R2: per-step launches, but each step is a proper LDS-tiled GEMM.
// Block = (p-chunk of 64) x (8 co x 4 gates = 32 conv-out rows), 256 threads.
// Grid (4, 8, 8) = 256 blocks.
//
// Phases per step-kernel:
//  1. stage cat = [x_t ; h_{t-1}] (128 ch x 66 p incl. halo) into LDS,
//     transposed to [p][ic] with 5-bit XOR swizzle so compute reads are
//     ds_read_b128, conflict-free (2 lanes/bank).
//  2. GEMM: each wave owns one gate g (=wave id): rows g*64+coz*8+k, k=0..7.
//     Weight addresses wave-uniform -> s_load; inputs from LDS b128.
//  3. conv_out (32 rows x 64 p) via LDS -> gate math (each thread needs all
//     4 gates of a co) -> coalesced stores. d_out doubles as recurrent state.

constexpr int Bn    = 8;
constexpr int Tn    = 128;
constexpr int CINn  = 64;
constexpr int COUTn = 64;
constexpr int Hn    = 256;
constexpr int ICAT  = CINn + COUTn;   // 128
constexpr int PP    = 64;             // p positions per block

__device__ __forceinline__ float sigmoidf_(float v) {
    return 1.0f / (1.0f + __expf(-v));
}

__global__ __launch_bounds__(256) void convlstm_step(
    const float* __restrict__ x,     // [B][T][CIN][H]
    const float* __restrict__ h0,    // [B][COUT][H]
    const float* __restrict__ c0,    // [B][COUT][H]
    const float* __restrict__ wg,    // [4*COUT][ICAT][3]
    const float* __restrict__ bias,  // [4*COUT]
    const float* __restrict__ wci,   // [COUT][H]
    const float* __restrict__ wcf,   // [COUT][H]
    const float* __restrict__ wco,   // [COUT][H]
    float* __restrict__ hs,          // [B][T][COUT][H]
    float* __restrict__ cs,          // [B][T][COUT][H]
    int t)
{
    // LDS: cat [66 rows(p)][128 ic] swizzled; conv_out [32][64]
    __shared__ float cat[66 * 128];       // 33.8 KB
    __shared__ float conv_out[32 * 64];   // 8 KB

    const int tid = threadIdx.x;
    const int p_l = tid & 63;             // lane = local p
    const int icg = tid >> 6;             // 0..3
    const int p0  = blockIdx.x * PP;
    const int b   = blockIdx.y;
    const int coz = blockIdx.z;           // co-chunk of 8

    const float* xt = x + (size_t)(b * Tn + t) * CINn * Hn;
    const float* hp = (t == 0) ? (h0 + (size_t)b * COUTn * Hn)
                               : (hs + (size_t)(b * Tn + (t - 1)) * COUTn * Hn);
    const float* cp = (t == 0) ? (c0 + (size_t)b * COUTn * Hn)
                               : (cs + (size_t)(b * Tn + (t - 1)) * COUTn * Hn);

    // ---- Phase 1: stage cat into LDS (transposed + swizzled) ----
    // interior: 128 ic x 64 p, thread (p_l, icg) covers ic = icc*4+icg
    {
        float vals[32];
#pragma unroll
        for (int icc = 0; icc < 32; ++icc) {
            const int ic = icc * 4 + icg;
            const float* src = (ic < CINn) ? (xt + (size_t)ic * Hn)
                                           : (hp + (size_t)(ic - CINn) * Hn);
            vals[icc] = src[p0 + p_l];
        }
        const int row = p_l + 1;
#pragma unroll
        for (int icc = 0; icc < 32; ++icc) {
            const int ic   = icc * 4 + icg;
            const int slot = (ic >> 2) ^ (row & 31);
            cat[row * 128 + slot * 4 + (ic & 3)] = vals[icc];
        }
        // halo columns (rows 0 and 65)
        if (tid < 128) {
            const int ic = tid;
            float v = 0.0f;
            if (p0 > 0) {
                const float* src = (ic < CINn) ? (xt + (size_t)ic * Hn)
                                               : (hp + (size_t)(ic - CINn) * Hn);
                v = src[p0 - 1];
            }
            const int slot = (ic >> 2);   // row 0: ^0
            cat[slot * 4 + (ic & 3)] = v;
        } else {
            const int ic = tid - 128;
            float v = 0.0f;
            if (p0 + PP < Hn) {
                const float* src = (ic < CINn) ? (xt + (size_t)ic * Hn)
                                               : (hp + (size_t)(ic - CINn) * Hn);
                v = src[p0 + PP];
            }
            const int slot = (ic >> 2) ^ (65 & 31);   // row 65
            cat[65 * 128 + slot * 4 + (ic & 3)] = v;
        }
    }
    __syncthreads();

    // ---- Phase 2: GEMM. wave w = gate w; rows chan0+k, k=0..7 ----
    const int wv    = __builtin_amdgcn_readfirstlane(tid >> 6);
    const int chan0 = wv * COUTn + coz * 8;     // conv-out channel base
    const float* wbase = wg + (size_t)chan0 * (ICAT * 3);

    float acc[8];
#pragma unroll
    for (int k = 0; k < 8; ++k) acc[k] = bias[chan0 + k];

    const float4* cat4 = (const float4*)cat;
    // rows read: p_l + d, d=0..2  (cat row = local p + 1, taps p-1,p,p+1)
    const int r0 = p_l, r1 = p_l + 1, r2 = p_l + 2;
    const int s0 = (r0 & 31), s1 = (r1 & 31), s2 = (r2 & 31);

#pragma unroll 2
    for (int icq = 0; icq < 32; ++icq) {
        const float4 a0 = cat4[r0 * 32 + (icq ^ s0)];
        const float4 a1 = cat4[r1 * 32 + (icq ^ s1)];
        const float4 a2 = cat4[r2 * 32 + (icq ^ s2)];
        const float in0[4] = {a0.x, a0.y, a0.z, a0.w};
        const float in1[4] = {a1.x, a1.y, a1.z, a1.w};
        const float in2[4] = {a2.x, a2.y, a2.z, a2.w};
#pragma unroll
        for (int k = 0; k < 8; ++k) {
            const float* wr = wbase + (size_t)k * (ICAT * 3) + icq * 12;
#pragma unroll
            for (int i = 0; i < 4; ++i) {
                acc[k] = fmaf(wr[3 * i + 0], in0[i],
                          fmaf(wr[3 * i + 1], in1[i],
                          fmaf(wr[3 * i + 2], in2[i], acc[k])));
            }
        }
    }

#pragma unroll
    for (int k = 0; k < 8; ++k)
        conv_out[(wv * 8 + k) * 64 + p_l] = acc[k];
    __syncthreads();

    // ---- Phase 3: gate math. thread (p_l, c2) handles co_l = c2*2+{0,1} ----
    const int c2 = tid >> 6;
    const int pg = p0 + p_l;
#pragma unroll
    for (int j = 0; j < 2; ++j) {
        const int co_l = c2 * 2 + j;
        const int co   = coz * 8 + co_l;
        const float pi = conv_out[(0 * 8 + co_l) * 64 + p_l];
        const float pf = conv_out[(1 * 8 + co_l) * 64 + p_l];
        const float pg_ = conv_out[(2 * 8 + co_l) * 64 + p_l];
        const float po = conv_out[(3 * 8 + co_l) * 64 + p_l];

        const size_t cidx = (size_t)co * Hn + pg;
        const float cprev = cp[cidx];
        const float iv = sigmoidf_(pi + wci[cidx] * cprev);
        const float fv = sigmoidf_(pf + wcf[cidx] * cprev);
        const float gv = tanhf(pg_);
        const float cn = fv * cprev + iv * gv;
        const float ov = sigmoidf_(po + wco[cidx] * cn);
        const float hn = ov * tanhf(cn);

        const size_t oidx = ((size_t)(b * Tn + t) * COUTn + co) * Hn + pg;
        hs[oidx] = hn;
        cs[oidx] = cn;
    }
}

extern "C" void kernel_launch(void* const* d_in, const int* in_sizes, int n_in,
                              void* d_out, int out_size, void* d_ws, size_t ws_size,
                              hipStream_t stream) {
    (void)in_sizes; (void)n_in; (void)out_size; (void)d_ws; (void)ws_size;

    const float* x    = (const float*)d_in[0];
    const float* h0   = (const float*)d_in[1];
    const float* c0   = (const float*)d_in[2];
    const float* w    = (const float*)d_in[3];
    const float* bias = (const float*)d_in[4];
    const float* wci  = (const float*)d_in[5];
    const float* wcf  = (const float*)d_in[6];
    const float* wco  = (const float*)d_in[7];

    float* hs = (float*)d_out;
    float* cs = hs + (size_t)Bn * Tn * COUTn * Hn;

    dim3 grid(Hn / PP, Bn, 8);   // (4, 8, 8) = 256 blocks
    for (int t = 0; t < Tn; ++t) {
        convlstm_step<<<grid, 256, 0, stream>>>(
            x, h0, c0, w, bias, wci, wcf, wco, hs, cs, t);
    }
}